// Round 12
// baseline (47.058 us; speedup 1.0000x reference)
//
#include <hip/hip_runtime.h>

#define NG   4000
#define EPG  512

__device__ inline float dot4(const float4 a, const float4 b) {
    return a.x * b.x + a.y * b.y + a.z * b.z + a.w * b.w;
}

// ---- prep: p = W1*(W2*(W3*1)); out[0..63]=p, out[64]=b1.q2, out[65]=b2.w3, out[66]=64*sum(b3)
__global__ __launch_bounds__(256) void prep_vec(
    const float* __restrict__ W1, const float* __restrict__ b1,
    const float* __restrict__ W2, const float* __restrict__ b2,
    const float* __restrict__ W3, const float* __restrict__ b3,
    float* __restrict__ out)
{
    __shared__ float w3[64], q2[64];
    const int t  = threadIdx.x;
    const int rg = t >> 4;           // row = 16*j + rg for float4 #j
    const int l16 = t & 15;

    const float4* W1_4 = (const float4*)W1;
    const float4* W2_4 = (const float4*)W2;
    const float4* W3_4 = (const float4*)W3;
    float4 a3[4], a2[4], a1[4];
    #pragma unroll
    for (int j = 0; j < 4; ++j) a3[j] = W3_4[t + 256 * j];
    #pragma unroll
    for (int j = 0; j < 4; ++j) a2[j] = W2_4[t + 256 * j];
    #pragma unroll
    for (int j = 0; j < 4; ++j) a1[j] = W1_4[t + 256 * j];
    float bb1 = 0.f, bb2 = 0.f, bb3 = 0.f;
    if (t < 64) { bb1 = b1[t]; bb2 = b2[t]; bb3 = b3[t]; }

    #pragma unroll
    for (int j = 0; j < 4; ++j) {
        float s = a3[j].x + a3[j].y + a3[j].z + a3[j].w;
        s += __shfl_down(s, 8, 16);
        s += __shfl_down(s, 4, 16);
        s += __shfl_down(s, 2, 16);
        s += __shfl_down(s, 1, 16);
        if (l16 == 0) w3[16 * j + rg] = s;
    }
    __syncthreads();

    {
        const float4 wc = ((const float4*)w3)[l16];
        #pragma unroll
        for (int j = 0; j < 4; ++j) {
            float s = dot4(a2[j], wc);
            s += __shfl_down(s, 8, 16);
            s += __shfl_down(s, 4, 16);
            s += __shfl_down(s, 2, 16);
            s += __shfl_down(s, 1, 16);
            if (l16 == 0) q2[16 * j + rg] = s;
        }
    }
    __syncthreads();

    {
        const float4 qc = ((const float4*)q2)[l16];
        #pragma unroll
        for (int j = 0; j < 4; ++j) {
            float s = dot4(a1[j], qc);
            s += __shfl_down(s, 8, 16);
            s += __shfl_down(s, 4, 16);
            s += __shfl_down(s, 2, 16);
            s += __shfl_down(s, 1, 16);
            if (l16 == 0) out[16 * j + rg] = s;
        }
    }

    if (t < 64) {
        float t1 = bb1 * q2[t];
        float t2 = bb2 * w3[t];
        float t3 = bb3;
        #pragma unroll
        for (int off = 32; off > 0; off >>= 1) {
            t1 += __shfl_down(t1, off, 64);
            t2 += __shfl_down(t2, off, 64);
            t3 += __shfl_down(t3, off, 64);
        }
        if (t == 0) { out[64] = t1; out[65] = t2; out[66] = 64.f * t3; }
    }
}

// ---- main: edge-domain scatter u-passes, 2.8 KB LDS, 7 barriers, 8 blocks/CU ----
__global__ __launch_bounds__(256, 8) void gcn3_scatter(
    const float* __restrict__ x, const int* __restrict__ ei,
    const float* __restrict__ pv, float* __restrict__ y, int etot)
{
    __shared__ int   deg4[4][64];                 // per-wave degree copies
    __shared__ float accA[64], accB[64], accC[64];
    __shared__ float zdA[64], zdB[64];
    __shared__ float dinvS[64], xp[64];

    const int g = blockIdx.x, t = threadIdx.x;
    const int w = t >> 6, lane = t & 63;
    const int base = g * 64;
    const int row = t >> 2, q4 = t & 3;

    // edges first (needed earliest, by deg scatter)
    const int2 sv = *(const int2*)(ei + (size_t)g * EPG + 2 * t);
    const int2 dv = *(const int2*)(ei + (size_t)etot + (size_t)g * EPG + 2 * t);

    // x loads: thread t covers 64 consecutive bytes -> wave reads 4 KB coalesced
    const float4* xg = (const float4*)(x + (size_t)g * 4096 + row * 64 + q4 * 16);
    const float4 xr0 = xg[0], xr1 = xg[1], xr2 = xg[2], xr3 = xg[3];

    // p slice (same 256 B for all blocks -> L1-hot)
    const float4* pp = (const float4*)(pv + q4 * 16);
    const float4 p0 = pp[0], p1 = pp[1], p2 = pp[2], p3 = pp[3];

    // zero: each wave its own deg copy; waves 1-3 zero acc buffers (in-order per wave)
    deg4[w][lane] = 0;
    if (w == 1) accA[lane] = 0.f;
    if (w == 2) accB[lane] = 0.f;
    if (w == 3) accC[lane] = 0.f;

    const int sa = sv.x - base, da = dv.x - base;
    const int sb = sv.y - base, db = dv.y - base;

    // degree scatter into own wave's copy (no barrier needed: same-wave in-order)
    atomicAdd(&deg4[w][da], 1);
    atomicAdd(&deg4[w][db], 1);

    // xp[r] = dot(x[r,:], p) — register math + 4-lane shfl reduce
    {
        float part = dot4(xr0, p0) + dot4(xr1, p1) + dot4(xr2, p2) + dot4(xr3, p3);
        part += __shfl_down(part, 2, 4);
        part += __shfl_down(part, 1, 4);
        if (q4 == 0) xp[row] = part;
    }
    __syncthreads();                                   // B1: deg, acc zeros, xp done

    float di = 0.f;
    if (t < 64) {
        const int ds = deg4[0][t] + deg4[1][t] + deg4[2][t] + deg4[3][t];
        di = rsqrtf((float)(ds + 1));                  // +1 = self-loop
        dinvS[t] = di;
        zdA[t] = di;                                   // zd for pass 1 (z = 1)
    }
    __syncthreads();                                   // B2

    // pass 1: acc[s] += zd[d] over edges
    atomicAdd(&accA[sa], zdA[da]);
    atomicAdd(&accA[sb], zdA[db]);
    __syncthreads();                                   // B3

    float u1 = 0.f;
    if (t < 64) {
        u1 = di * accA[t] + di * di;                   // zprev = 1
        zdB[t] = di * u1;
    }
    __syncthreads();                                   // B4

    // pass 2
    atomicAdd(&accB[sa], zdB[da]);
    atomicAdd(&accB[sb], zdB[db]);
    __syncthreads();                                   // B5

    float u2 = 0.f;
    if (t < 64) {
        u2 = di * accB[t] + di * di * u1;
        zdA[t] = di * u2;                              // reuse zdA for pass 3
    }
    __syncthreads();                                   // B6

    // pass 3
    atomicAdd(&accC[sa], zdA[da]);
    atomicAdd(&accC[sb], zdA[db]);
    __syncthreads();                                   // B7

    if (t < 64) {
        const float u3 = di * accC[t] + di * di * u2;
        float r  = u3 * xp[t];
        float a1 = u1;
        float a2 = u2;
        #pragma unroll
        for (int off = 32; off > 0; off >>= 1) {
            r  += __shfl_down(r,  off, 64);
            a1 += __shfl_down(a1, off, 64);
            a2 += __shfl_down(a2, off, 64);
        }
        if (t == 0) {
            const float beta1 = pv[64], beta2 = pv[65], beta3 = pv[66];
            y[g] = (r + a2 * beta1 + a1 * beta2 + beta3) * (1.0f / 4096.0f);
        }
    }
}

extern "C" void kernel_launch(void* const* d_in, const int* in_sizes, int n_in,
                              void* d_out, int out_size, void* d_ws, size_t ws_size,
                              hipStream_t stream) {
    const float* x  = (const float*)d_in[0];
    const int*   ei = (const int*)  d_in[1];
    const float* W1 = (const float*)d_in[2];
    const float* b1 = (const float*)d_in[3];
    const float* W2 = (const float*)d_in[4];
    const float* b2 = (const float*)d_in[5];
    const float* W3 = (const float*)d_in[6];
    const float* b3 = (const float*)d_in[7];
    float* y = (float*)d_out;
    const int etot = in_sizes[1] / 2;     // 2,048,000

    float* pv = (float*)d_ws;             // 67 floats
    hipLaunchKernelGGL(prep_vec, dim3(1), dim3(256), 0, stream,
                       W1, b1, W2, b2, W3, b3, pv);
    hipLaunchKernelGGL(gcn3_scatter, dim3(NG), dim3(256), 0, stream,
                       x, ei, pv, y, etot);
}

// Round 13
// 29.085 us; speedup vs baseline: 1.6179x; 1.6179x over previous
//
#include <hip/hip_runtime.h>

#define NG      4000
#define EPG     512
#define CSTRIDE 36   // ints per Cnt row: 16B-aligned q4 slices -> b128 reads, uniform banks

__device__ inline float dot4(const float4 a, const float4 b) {
    return a.x * b.x + a.y * b.y + a.z * b.z + a.w * b.w;
}

// Single fused kernel: per-block W-collapse (p, betas) + graph chain + x contraction.
// y*4096 = sum_r u3[r]*dot(x[r,:],p) + s2*beta1 + s1*beta2 + beta3
__global__ __launch_bounds__(256, 6) void gcn3_one(
    const float* __restrict__ x, const int* __restrict__ ei,
    const float* __restrict__ W1, const float* __restrict__ b1,
    const float* __restrict__ W2, const float* __restrict__ b2,
    const float* __restrict__ W3, const float* __restrict__ b3,
    float* __restrict__ y, int etot)
{
    __shared__ int   Cnt[64 * CSTRIDE];   // packed u16x2 counts  (9216 B)
    __shared__ int   deg4[4][64];         // per-wave degree copies (1024 B)
    __shared__ float w3S[64], q2S[64], pS[64];
    __shared__ float dinvS[64], zdA[64], zdB[64];
    __shared__ float u1S[64], u2S[64], u3S[64], xpS[64];
    __shared__ float betaS[3];

    const int g = blockIdx.x, t = threadIdx.x, w = t >> 6;
    const int base = g * 64;
    const int row = t >> 2,  q4  = t & 3;    // graph/gather mapping
    const int rg  = t >> 4,  l16 = t & 15;   // W-stage mapping (row = 16j+rg)

    // ---- issue global loads up front ----
    const float4* xg = (const float4*)(x + (size_t)g * 4096 + row * 64 + q4 * 16);
    const float4 xr0 = xg[0], xr1 = xg[1], xr2 = xg[2], xr3 = xg[3];

    const int2 sv = *(const int2*)(ei + (size_t)g * EPG + 2 * t);
    const int2 dv = *(const int2*)(ei + (size_t)etot + (size_t)g * EPG + 2 * t);

    const float4* W3_4 = (const float4*)W3;
    const float4* W2_4 = (const float4*)W2;
    const float4* W1_4 = (const float4*)W1;
    float4 aW[4];
    #pragma unroll
    for (int j = 0; j < 4; ++j) aW[j] = W3_4[t + 256 * j];
    float bb1 = 0.f, bb2 = 0.f, bb3 = 0.f;
    if (t < 64) { bb1 = b1[t]; bb2 = b2[t]; bb3 = b3[t]; }

    // ---- zero Cnt + deg ----
    {
        const int4 z = {0, 0, 0, 0};
        int4* c4 = (int4*)Cnt;
        c4[t] = z; c4[t + 256] = z;
        if (t < 64) c4[t + 512] = z;          // 576 int4 total
        ((int*)deg4)[t] = 0;
    }
    __syncthreads();                                   // B1

    // ---- phase A: edge scatter (int atomics) + w3 = W3 rowsum ----
    {
        const int sa = sv.x - base, da = dv.x - base;
        const int sb = sv.y - base, db = dv.y - base;
        atomicAdd(&deg4[w][da], 1);
        atomicAdd(&deg4[w][db], 1);
        atomicAdd(&Cnt[sa * CSTRIDE + (da >> 1)], 1 << ((da & 1) * 16));
        atomicAdd(&Cnt[sb * CSTRIDE + (db >> 1)], 1 << ((db & 1) * 16));
    }
    #pragma unroll
    for (int j = 0; j < 4; ++j) {
        float s = aW[j].x + aW[j].y + aW[j].z + aW[j].w;
        s += __shfl_down(s, 8, 16);
        s += __shfl_down(s, 4, 16);
        s += __shfl_down(s, 2, 16);
        s += __shfl_down(s, 1, 16);
        if (l16 == 0) w3S[16 * j + rg] = s;
    }
    #pragma unroll
    for (int j = 0; j < 4; ++j) aW[j] = W2_4[t + 256 * j];   // reload for stage 2
    __syncthreads();                                   // B2: deg, Cnt, w3 ready

    // ---- phase B: dinv/zdA + q2 = W2*w3 ----
    if (t < 64) {
        const int ds = deg4[0][t] + deg4[1][t] + deg4[2][t] + deg4[3][t];
        const float di = rsqrtf((float)(ds + 1));      // +1 = self-loop
        dinvS[t] = di;
        zdA[t] = di;                                   // zd for pass 1 (z = 1)
    }
    {
        const float4 wc = ((const float4*)w3S)[l16];
        #pragma unroll
        for (int j = 0; j < 4; ++j) {
            float s = dot4(aW[j], wc);
            s += __shfl_down(s, 8, 16);
            s += __shfl_down(s, 4, 16);
            s += __shfl_down(s, 2, 16);
            s += __shfl_down(s, 1, 16);
            if (l16 == 0) q2S[16 * j + rg] = s;
        }
    }
    #pragma unroll
    for (int j = 0; j < 4; ++j) aW[j] = W1_4[t + 256 * j];   // reload for stage 3
    __syncthreads();                                   // B3: zdA, q2 ready

    // u-pass gather: 2 x int4 Cnt + 4 x float4 zin per thread (R11-proven)
    auto upass = [&](const float* zin, float* zout, const float* uprev, float* u) {
        const int4* rp = (const int4*)(Cnt + row * CSTRIDE + q4 * 8);
        const int4 c0 = rp[0], c1 = rp[1];
        const float4* zp = (const float4*)(zin + q4 * 16);
        const float4 z0 = zp[0], z1 = zp[1], z2 = zp[2], z3 = zp[3];
        float acc = 0.f;
        acc += (float)((unsigned)c0.x & 0xffffu) * z0.x + (float)((unsigned)c0.x >> 16) * z0.y;
        acc += (float)((unsigned)c0.y & 0xffffu) * z0.z + (float)((unsigned)c0.y >> 16) * z0.w;
        acc += (float)((unsigned)c0.z & 0xffffu) * z1.x + (float)((unsigned)c0.z >> 16) * z1.y;
        acc += (float)((unsigned)c0.w & 0xffffu) * z1.z + (float)((unsigned)c0.w >> 16) * z1.w;
        acc += (float)((unsigned)c1.x & 0xffffu) * z2.x + (float)((unsigned)c1.x >> 16) * z2.y;
        acc += (float)((unsigned)c1.y & 0xffffu) * z2.z + (float)((unsigned)c1.y >> 16) * z2.w;
        acc += (float)((unsigned)c1.z & 0xffffu) * z3.x + (float)((unsigned)c1.z >> 16) * z3.y;
        acc += (float)((unsigned)c1.w & 0xffffu) * z3.z + (float)((unsigned)c1.w >> 16) * z3.w;
        acc += __shfl_down(acc, 2, 4);
        acc += __shfl_down(acc, 1, 4);
        if (q4 == 0) {
            const float di = dinvS[row];
            const float zp_ = uprev ? uprev[row] : 1.0f;
            const float uv = di * acc + di * di * zp_;
            u[row] = uv;
            if (zout) zout[row] = di * uv;
        }
    };

    // ---- phase C: u-pass 1 + p = W1*q2 + betas ----
    upass(zdA, zdB, nullptr, u1S);
    {
        const float4 qc = ((const float4*)q2S)[l16];
        #pragma unroll
        for (int j = 0; j < 4; ++j) {
            float s = dot4(aW[j], qc);
            s += __shfl_down(s, 8, 16);
            s += __shfl_down(s, 4, 16);
            s += __shfl_down(s, 2, 16);
            s += __shfl_down(s, 1, 16);
            if (l16 == 0) pS[16 * j + rg] = s;
        }
    }
    if (t < 64) {
        float t1 = bb1 * q2S[t];
        float t2 = bb2 * w3S[t];
        float t3 = bb3;
        #pragma unroll
        for (int off = 32; off > 0; off >>= 1) {
            t1 += __shfl_down(t1, off, 64);
            t2 += __shfl_down(t2, off, 64);
            t3 += __shfl_down(t3, off, 64);
        }
        if (t == 0) { betaS[0] = t1; betaS[1] = t2; betaS[2] = 64.f * t3; }
    }
    __syncthreads();                                   // B4: u1, zdB, p, betas ready

    // ---- phase D: u-pass 2 + xp = x.p (x regs held since top; p now ready) ----
    upass(zdB, zdA, u1S, u2S);
    {
        const float4* pp4 = (const float4*)(pS + q4 * 16);
        float part = dot4(xr0, pp4[0]) + dot4(xr1, pp4[1])
                   + dot4(xr2, pp4[2]) + dot4(xr3, pp4[3]);
        part += __shfl_down(part, 2, 4);
        part += __shfl_down(part, 1, 4);
        if (q4 == 0) xpS[row] = part;
    }
    __syncthreads();                                   // B5: u2, zdA, xp ready

    // ---- phase E: u-pass 3 ----
    upass(zdA, nullptr, u2S, u3S);
    __syncthreads();                                   // B6: u3 ready

    // ---- final: r = u3.xp, s1 = sum(u1), s2 = sum(u2) ----
    if (t < 64) {
        float r  = u3S[t] * xpS[t];
        float a1 = u1S[t];
        float a2 = u2S[t];
        #pragma unroll
        for (int off = 32; off > 0; off >>= 1) {
            r  += __shfl_down(r,  off, 64);
            a1 += __shfl_down(a1, off, 64);
            a2 += __shfl_down(a2, off, 64);
        }
        if (t == 0) {
            y[g] = (r + a2 * betaS[0] + a1 * betaS[1] + betaS[2]) * (1.0f / 4096.0f);
        }
    }
}

extern "C" void kernel_launch(void* const* d_in, const int* in_sizes, int n_in,
                              void* d_out, int out_size, void* d_ws, size_t ws_size,
                              hipStream_t stream) {
    const float* x  = (const float*)d_in[0];
    const int*   ei = (const int*)  d_in[1];
    const float* W1 = (const float*)d_in[2];
    const float* b1 = (const float*)d_in[3];
    const float* W2 = (const float*)d_in[4];
    const float* b2 = (const float*)d_in[5];
    const float* W3 = (const float*)d_in[6];
    const float* b3 = (const float*)d_in[7];
    float* y = (float*)d_out;
    const int etot = in_sizes[1] / 2;     // 2,048,000

    hipLaunchKernelGGL(gcn3_one, dim3(NG), dim3(256), 0, stream,
                       x, ei, W1, b1, W2, b2, W3, b3, y, etot);
}

// Round 14
// 25.606 us; speedup vs baseline: 1.8378x; 1.1359x over previous
//
#include <hip/hip_runtime.h>

#define NG      4000
#define EPG     512
#define CSTRIDE 36   // ints per Cnt row: 16B-aligned q4 slices -> b128 reads, uniform banks

__device__ inline float dot4(const float4 a, const float4 b) {
    return a.x * b.x + a.y * b.y + a.z * b.z + a.w * b.w;
}
__device__ inline float lo16(int v) { return (float)((unsigned)v & 0xffffu); }
__device__ inline float hi16(int v) { return (float)((unsigned)v >> 16); }

// ---- prep: p = W1*(W2*(W3*1)); out[0..63]=p, out[64]=b1.q2, out[65]=b2.w3, out[66]=64*sum(b3)
__global__ __launch_bounds__(256) void prep_vec(
    const float* __restrict__ W1, const float* __restrict__ b1,
    const float* __restrict__ W2, const float* __restrict__ b2,
    const float* __restrict__ W3, const float* __restrict__ b3,
    float* __restrict__ out)
{
    __shared__ float w3[64], q2[64];
    const int t  = threadIdx.x;
    const int rg = t >> 4;           // row = 16*j + rg for float4 #j
    const int l16 = t & 15;

    const float4* W1_4 = (const float4*)W1;
    const float4* W2_4 = (const float4*)W2;
    const float4* W3_4 = (const float4*)W3;
    float4 a3[4], a2[4], a1[4];
    #pragma unroll
    for (int j = 0; j < 4; ++j) a3[j] = W3_4[t + 256 * j];
    #pragma unroll
    for (int j = 0; j < 4; ++j) a2[j] = W2_4[t + 256 * j];
    #pragma unroll
    for (int j = 0; j < 4; ++j) a1[j] = W1_4[t + 256 * j];
    float bb1 = 0.f, bb2 = 0.f, bb3 = 0.f;
    if (t < 64) { bb1 = b1[t]; bb2 = b2[t]; bb3 = b3[t]; }

    #pragma unroll
    for (int j = 0; j < 4; ++j) {
        float s = a3[j].x + a3[j].y + a3[j].z + a3[j].w;
        s += __shfl_down(s, 8, 16);
        s += __shfl_down(s, 4, 16);
        s += __shfl_down(s, 2, 16);
        s += __shfl_down(s, 1, 16);
        if (l16 == 0) w3[16 * j + rg] = s;
    }
    __syncthreads();

    {
        const float4 wc = ((const float4*)w3)[l16];
        #pragma unroll
        for (int j = 0; j < 4; ++j) {
            float s = dot4(a2[j], wc);
            s += __shfl_down(s, 8, 16);
            s += __shfl_down(s, 4, 16);
            s += __shfl_down(s, 2, 16);
            s += __shfl_down(s, 1, 16);
            if (l16 == 0) q2[16 * j + rg] = s;
        }
    }
    __syncthreads();

    {
        const float4 qc = ((const float4*)q2)[l16];
        #pragma unroll
        for (int j = 0; j < 4; ++j) {
            float s = dot4(a1[j], qc);
            s += __shfl_down(s, 8, 16);
            s += __shfl_down(s, 4, 16);
            s += __shfl_down(s, 2, 16);
            s += __shfl_down(s, 1, 16);
            if (l16 == 0) out[16 * j + rg] = s;
        }
    }

    if (t < 64) {
        float t1 = bb1 * q2[t];
        float t2 = bb2 * w3[t];
        float t3 = bb3;
        #pragma unroll
        for (int off = 32; off > 0; off >>= 1) {
            t1 += __shfl_down(t1, off, 64);
            t2 += __shfl_down(t2, off, 64);
            t3 += __shfl_down(t3, off, 64);
        }
        if (t == 0) { out[64] = t1; out[65] = t2; out[66] = 64.f * t3; }
    }
}

// ---- main: 5 barriers; xp contraction deferred to last phase (x-load slack) ----
__global__ __launch_bounds__(256, 8) void gcn3_collapse4(
    const float* __restrict__ x, const int* __restrict__ ei,
    const float* __restrict__ pv, float* __restrict__ y, int etot)
{
    __shared__ int   Cnt[64 * CSTRIDE];   // packed u16x2 counts  (9216 B)
    __shared__ int   deg2[2][64];         // 2 degree copies      (512 B)
    __shared__ float zdB[64], zdA[64];
    __shared__ float u1S[64], u2S[64], u3S[64], xpS[64];

    const int g = blockIdx.x, t = threadIdx.x;
    const int w = t >> 6;
    const int base = g * 64;
    const int row = t >> 2, q4 = t & 3;

    // edges first (needed in phase A)
    const int2 sv = *(const int2*)(ei + (size_t)g * EPG + 2 * t);
    const int2 dv = *(const int2*)(ei + (size_t)etot + (size_t)g * EPG + 2 * t);

    // x loads issued now, consumed only in the LAST phase (4 phases of latency slack)
    const float4* xg = (const float4*)(x + (size_t)g * 4096 + row * 64 + q4 * 16);
    const float4 xr0 = xg[0], xr1 = xg[1], xr2 = xg[2], xr3 = xg[3];

    // zero Cnt + deg2
    {
        const int4 z = {0, 0, 0, 0};
        int4* c4 = (int4*)Cnt;
        c4[t] = z; c4[t + 256] = z;
        if (t < 64) c4[t + 512] = z;
        if (t < 128) ((int*)deg2)[t] = 0;
    }
    __syncthreads();                                   // B1

    // ---- phase A: deterministic integer scatter ----
    {
        const int sa = sv.x - base, da = dv.x - base;
        const int sb = sv.y - base, db = dv.y - base;
        atomicAdd(&deg2[w & 1][da], 1);
        atomicAdd(&deg2[w & 1][db], 1);
        atomicAdd(&Cnt[sa * CSTRIDE + (da >> 1)], 1 << ((da & 1) * 16));
        atomicAdd(&Cnt[sb * CSTRIDE + (db >> 1)], 1 << ((db & 1) * 16));
    }
    __syncthreads();                                   // B2

    // gather: acc = sum_d Cnt[row][d] * z[d] over this thread's 16-d slice, reduced to q4==0
    auto gather = [&](float4 z0, float4 z1, float4 z2, float4 z3) -> float {
        const int4* rp = (const int4*)(Cnt + row * CSTRIDE + q4 * 8);
        const int4 c0 = rp[0], c1 = rp[1];
        float acc = 0.f;
        acc += lo16(c0.x) * z0.x + hi16(c0.x) * z0.y;
        acc += lo16(c0.y) * z0.z + hi16(c0.y) * z0.w;
        acc += lo16(c0.z) * z1.x + hi16(c0.z) * z1.y;
        acc += lo16(c0.w) * z1.z + hi16(c0.w) * z1.w;
        acc += lo16(c1.x) * z2.x + hi16(c1.x) * z2.y;
        acc += lo16(c1.y) * z2.z + hi16(c1.y) * z2.w;
        acc += lo16(c1.z) * z3.x + hi16(c1.z) * z3.y;
        acc += lo16(c1.w) * z3.z + hi16(c1.w) * z3.w;
        acc += __shfl_down(acc, 2, 4);
        acc += __shfl_down(acc, 1, 4);
        return acc;                                    // valid in q4==0 lanes
    };

    // ---- phase B: pass 1, zin = dinv computed directly from deg (no extra barrier) ----
    float di = 0.f, u1r = 0.f, u2r = 0.f;
    {
        const int db_ = q4 * 16;
        float4 z0, z1, z2, z3;
        {
            const int4 a0 = *(const int4*)(&deg2[0][db_ +  0]);
            const int4 b0 = *(const int4*)(&deg2[1][db_ +  0]);
            const int4 a1_ = *(const int4*)(&deg2[0][db_ + 4]);
            const int4 b1_ = *(const int4*)(&deg2[1][db_ + 4]);
            const int4 a2_ = *(const int4*)(&deg2[0][db_ + 8]);
            const int4 b2_ = *(const int4*)(&deg2[1][db_ + 8]);
            const int4 a3_ = *(const int4*)(&deg2[0][db_ + 12]);
            const int4 b3_ = *(const int4*)(&deg2[1][db_ + 12]);
            z0.x = rsqrtf((float)(a0.x + b0.x + 1));  z0.y = rsqrtf((float)(a0.y + b0.y + 1));
            z0.z = rsqrtf((float)(a0.z + b0.z + 1));  z0.w = rsqrtf((float)(a0.w + b0.w + 1));
            z1.x = rsqrtf((float)(a1_.x + b1_.x + 1)); z1.y = rsqrtf((float)(a1_.y + b1_.y + 1));
            z1.z = rsqrtf((float)(a1_.z + b1_.z + 1)); z1.w = rsqrtf((float)(a1_.w + b1_.w + 1));
            z2.x = rsqrtf((float)(a2_.x + b2_.x + 1)); z2.y = rsqrtf((float)(a2_.y + b2_.y + 1));
            z2.z = rsqrtf((float)(a2_.z + b2_.z + 1)); z2.w = rsqrtf((float)(a2_.w + b2_.w + 1));
            z3.x = rsqrtf((float)(a3_.x + b3_.x + 1)); z3.y = rsqrtf((float)(a3_.y + b3_.y + 1));
            z3.z = rsqrtf((float)(a3_.z + b3_.z + 1)); z3.w = rsqrtf((float)(a3_.w + b3_.w + 1));
        }
        const float acc1 = gather(z0, z1, z2, z3);
        if (q4 == 0) {
            di = rsqrtf((float)(deg2[0][row] + deg2[1][row] + 1));
            u1r = di * acc1 + di * di;                 // zprev = 1
            u1S[row] = u1r;
            zdB[row] = di * u1r;
        }
    }
    __syncthreads();                                   // B3

    // ---- phase C: pass 2 ----
    {
        const float4* zp = (const float4*)(zdB + q4 * 16);
        const float acc2 = gather(zp[0], zp[1], zp[2], zp[3]);
        if (q4 == 0) {
            u2r = di * acc2 + di * di * u1r;
            u2S[row] = u2r;
            zdA[row] = di * u2r;
        }
    }
    __syncthreads();                                   // B4

    // ---- phase D: pass 3 + xp contraction (x regs finally consumed) ----
    {
        const float4* zp = (const float4*)(zdA + q4 * 16);
        const float acc3 = gather(zp[0], zp[1], zp[2], zp[3]);
        if (q4 == 0) u3S[row] = di * acc3 + di * di * u2r;
    }
    {
        const float4* pp4 = (const float4*)(pv + q4 * 16);
        float part = dot4(xr0, pp4[0]) + dot4(xr1, pp4[1])
                   + dot4(xr2, pp4[2]) + dot4(xr3, pp4[3]);
        part += __shfl_down(part, 2, 4);
        part += __shfl_down(part, 1, 4);
        if (q4 == 0) xpS[row] = part;
    }
    __syncthreads();                                   // B5

    // ---- final: r = u3.xp, s1 = sum(u1), s2 = sum(u2) ----
    if (t < 64) {
        float r  = u3S[t] * xpS[t];
        float a1 = u1S[t];
        float a2 = u2S[t];
        #pragma unroll
        for (int off = 32; off > 0; off >>= 1) {
            r  += __shfl_down(r,  off, 64);
            a1 += __shfl_down(a1, off, 64);
            a2 += __shfl_down(a2, off, 64);
        }
        if (t == 0) {
            const float beta1 = pv[64], beta2 = pv[65], beta3 = pv[66];
            y[g] = (r + a2 * beta1 + a1 * beta2 + beta3) * (1.0f / 4096.0f);
        }
    }
}

extern "C" void kernel_launch(void* const* d_in, const int* in_sizes, int n_in,
                              void* d_out, int out_size, void* d_ws, size_t ws_size,
                              hipStream_t stream) {
    const float* x  = (const float*)d_in[0];
    const int*   ei = (const int*)  d_in[1];
    const float* W1 = (const float*)d_in[2];
    const float* b1 = (const float*)d_in[3];
    const float* W2 = (const float*)d_in[4];
    const float* b2 = (const float*)d_in[5];
    const float* W3 = (const float*)d_in[6];
    const float* b3 = (const float*)d_in[7];
    float* y = (float*)d_out;
    const int etot = in_sizes[1] / 2;     // 2,048,000

    float* pv = (float*)d_ws;             // 67 floats
    hipLaunchKernelGGL(prep_vec, dim3(1), dim3(256), 0, stream,
                       W1, b1, W2, b2, W3, b3, pv);
    hipLaunchKernelGGL(gcn3_collapse4, dim3(NG), dim3(256), 0, stream,
                       x, ei, pv, y, etot);
}